// Round 4
// baseline (591.328 us; speedup 1.0000x reference)
//
#include <hip/hip_runtime.h>
#include <hip/hip_bf16.h>
#include <hip/hip_fp16.h>
#include <math.h>

#define NEG_SLOPE 0.2f
#define NPART 8          // one dst-partition per XCD for scatter L2 locality
#define CSR_BLOCKS 1024  // 128 blocks per partition

// ---------------------------------------------------------------------------
// CSR build. edge_index int32, layout [src[0..E), dst[0..E)]; self-loops
// implicit (edge id >= E -> s=d=id-E).
// ---------------------------------------------------------------------------
__global__ void hist_kernel(const int* __restrict__ ei, int E, int n,
                            int* __restrict__ counts) {
    int Etot = E + n;
    int stride = gridDim.x * blockDim.x;
    for (int i = blockIdx.x * blockDim.x + threadIdx.x; i < Etot; i += stride) {
        int d = (i < E) ? ei[E + i] : (i - E);
        if ((unsigned)d < (unsigned)n) atomicAdd(&counts[d], 1);
    }
}

// Partitioned scatter: partition p owns dst range [lo,hi); its col/cursor
// region stays resident in one XCD L2 -> full-line writebacks (R3 win).
__global__ void scatter_part_kernel(const int* __restrict__ ei, int E, int n,
                                    int* __restrict__ cursor,
                                    int* __restrict__ col) {
    int pid = blockIdx.x & (NPART - 1);
    int bid = blockIdx.x >> 3;
    int nb  = gridDim.x >> 3;
    int lo = (int)((long long)pid * n / NPART);
    int hi = (int)((long long)(pid + 1) * n / NPART);
    int Etot = E + n;
    int stride = nb * blockDim.x;
    for (int i = bid * blockDim.x + threadIdx.x; i < Etot; i += stride) {
        int d = (i < E) ? ei[E + i] : (i - E);
        if (d >= lo && d < hi) {
            int s = (i < E) ? ei[i] : d;
            if ((unsigned)s < (unsigned)n) {
                int pos = atomicAdd(&cursor[d], 1);
                col[pos] = s;
            }
        }
    }
}

// ---------------------------------------------------------------------------
// Hierarchical exclusive scan of counts[n] -> row_ptr[n+1], cursor[n]
// ---------------------------------------------------------------------------
__global__ void scan1_kernel(const int* __restrict__ counts,
                             int* __restrict__ bsum, int n) {
    __shared__ int sm[256];
    int i = blockIdx.x * 256 + threadIdx.x;
    sm[threadIdx.x] = (i < n) ? counts[i] : 0;
    __syncthreads();
    for (int off = 128; off; off >>= 1) {
        if (threadIdx.x < off) sm[threadIdx.x] += sm[threadIdx.x + off];
        __syncthreads();
    }
    if (threadIdx.x == 0) bsum[blockIdx.x] = sm[0];
}

__global__ void scan2_kernel(int* __restrict__ bsum, int nb) {
    __shared__ int sm[256];
    int t = threadIdx.x;
    int v = (t < nb) ? bsum[t] : 0;
    sm[t] = v;
    __syncthreads();
    int x = v;
    for (int off = 1; off < 256; off <<= 1) {
        int y = (t >= off) ? sm[t - off] : 0;
        __syncthreads();
        x += y;
        sm[t] = x;
        __syncthreads();
    }
    if (t < nb) bsum[t] = x - v;
    if (t == nb - 1) bsum[nb] = x;
}

__global__ void scan3_kernel(const int* __restrict__ counts,
                             const int* __restrict__ bsum,
                             int* __restrict__ row_ptr,
                             int* __restrict__ cursor, int n, int nb) {
    __shared__ int sm[256];
    int t = threadIdx.x;
    int i = blockIdx.x * 256 + t;
    int v = (i < n) ? counts[i] : 0;
    sm[t] = v;
    __syncthreads();
    int x = v;
    for (int off = 1; off < 256; off <<= 1) {
        int y = (t >= off) ? sm[t - off] : 0;
        __syncthreads();
        x += y;
        sm[t] = x;
        __syncthreads();
    }
    int excl = bsum[blockIdx.x] + x - v;
    if (i < n) { row_ptr[i] = excl; cursor[i] = excl; }
    if (i == 0) row_ptr[n] = bsum[nb];
}

// ---------------------------------------------------------------------------
// Transform layer 1 (both branches): h = x@W as PLANAR fp16 tables (3.2 MB
// each -> fits one XCD L2 for the gather pass), es/ed planar fp32.
// ---------------------------------------------------------------------------
__global__ void t1_fused_kernel(const float* __restrict__ x,
                                const float* __restrict__ Wc,
                                const float* __restrict__ Wr,
                                const float* __restrict__ asc,
                                const float* __restrict__ adc,
                                const float* __restrict__ asr,
                                const float* __restrict__ adr,
                                __half* __restrict__ hc,
                                __half* __restrict__ hr,
                                float* __restrict__ esc,
                                float* __restrict__ edc,
                                float* __restrict__ esr,
                                float* __restrict__ edr, int n) {
    __shared__ float Wsc[64 * 32];
    __shared__ float Wsr[64 * 32];
    for (int i = threadIdx.x; i < 64 * 32; i += blockDim.x) {
        Wsc[i] = Wc[i];
        Wsr[i] = Wr[i];
    }
    __syncthreads();
    int group = (blockIdx.x * blockDim.x + threadIdx.x) >> 5;
    int f = threadIdx.x & 31;
    if (group >= n) return;
    float x0 = x[group * 64 + f];
    float x1 = x[group * 64 + 32 + f];
    float ac = 0.f, ar = 0.f;
#pragma unroll
    for (int k = 0; k < 64; ++k) {
        float xv = (k < 32) ? __shfl(x0, k, 32) : __shfl(x1, k - 32, 32);
        ac = fmaf(xv, Wsc[k * 32 + f], ac);
        ar = fmaf(xv, Wsr[k * 32 + f], ar);
    }
    hc[group * 32 + f] = __float2half(ac);
    hr[group * 32 + f] = __float2half(ar);
    float psc = ac * asc[f], pdc = ac * adc[f];
    float psr = ar * asr[f], pdr = ar * adr[f];
#pragma unroll
    for (int off = 16; off; off >>= 1) {
        psc += __shfl_xor(psc, off, 32);
        pdc += __shfl_xor(pdc, off, 32);
        psr += __shfl_xor(psr, off, 32);
        pdr += __shfl_xor(pdr, off, 32);
    }
    if (f == 0) {
        esc[group] = psc; edc[group] = pdc;
        esr[group] = psr; edr[group] = pdr;
    }
}

// Transform layer 2 (both branches), planar fp32 g inputs -> planar fp16 h
__global__ void t2_fused_kernel(const float* __restrict__ gc,
                                const float* __restrict__ gr,
                                const float* __restrict__ Wc,
                                const float* __restrict__ Wr,
                                const float* __restrict__ asc,
                                const float* __restrict__ adc,
                                const float* __restrict__ asr,
                                const float* __restrict__ adr,
                                __half* __restrict__ hc,
                                __half* __restrict__ hr,
                                float* __restrict__ esc,
                                float* __restrict__ edc,
                                float* __restrict__ esr,
                                float* __restrict__ edr, int n) {
    __shared__ float Wsc[32 * 32];
    __shared__ float Wsr[32 * 32];
    for (int i = threadIdx.x; i < 32 * 32; i += blockDim.x) {
        Wsc[i] = Wc[i];
        Wsr[i] = Wr[i];
    }
    __syncthreads();
    int group = (blockIdx.x * blockDim.x + threadIdx.x) >> 5;
    int f = threadIdx.x & 31;
    if (group >= n) return;
    float vc = gc[group * 32 + f];
    float vr = gr[group * 32 + f];
    float ac = 0.f, ar = 0.f;
#pragma unroll
    for (int k = 0; k < 32; ++k) {
        float xc = __shfl(vc, k, 32);
        float xr = __shfl(vr, k, 32);
        ac = fmaf(xc, Wsc[k * 32 + f], ac);
        ar = fmaf(xr, Wsr[k * 32 + f], ar);
    }
    hc[group * 32 + f] = __float2half(ac);
    hr[group * 32 + f] = __float2half(ar);
    float psc = ac * asc[f], pdc = ac * adc[f];
    float psr = ar * asr[f], pdr = ar * adr[f];
#pragma unroll
    for (int off = 16; off; off >>= 1) {
        psc += __shfl_xor(psc, off, 32);
        pdc += __shfl_xor(pdc, off, 32);
        psr += __shfl_xor(psr, off, 32);
        pdr += __shfl_xor(pdr, off, 32);
    }
    if (f == 0) {
        esc[group] = psc; edc[group] = pdc;
        esr[group] = psr; edr[group] = pdr;
    }
}

// ---------------------------------------------------------------------------
// Single-branch online-softmax aggregation core. One 32-lane group per dst,
// lane f owns feature f. h is planar fp16 (3.2 MB table -> L2-resident).
// Full 32-edge chunks take a fully-unrolled path (32 independent gathers in
// flight); tail chunk takes the dynamic loop.
// ---------------------------------------------------------------------------
__device__ __forceinline__ void agg_core1(const int* __restrict__ row_ptr,
                                          const int* __restrict__ col,
                                          const __half* __restrict__ h,
                                          const float* __restrict__ es,
                                          float edv, int d, int f,
                                          float& out_acc, float& out_l) {
    int beg = row_ptr[d], end = row_ptr[d + 1];
    float m = -INFINITY, l = 0.f, acc = 0.f;
    for (int base = beg; base < end; base += 32) {
        int rem = end - base;
        bool valid = f < rem;
        int s = valid ? col[base + f] : 0;
        float a = -INFINITY;
        if (valid) {
            float t = es[s] + edv;
            a = (t > 0.f) ? t : NEG_SLOPE * t;
        }
        float cm = a;
#pragma unroll
        for (int off = 16; off; off >>= 1) cm = fmaxf(cm, __shfl_xor(cm, off, 32));
        float mn = fmaxf(m, cm);
        float sc = __expf(m - mn);     // first chunk: exp(-inf)=0
        l *= sc; acc *= sc; m = mn;
        float ex = valid ? __expf(a - mn) : 0.f;
        l += ex;
        if (rem >= 32) {
#pragma unroll
            for (int j = 0; j < 32; ++j) {
                float w = __shfl(ex, j, 32);
                int sj = __shfl(s, j, 32);
                acc = fmaf(__half2float(h[sj * 32 + f]), w, acc);
            }
        } else {
            for (int j = 0; j < rem; ++j) {
                float w = __shfl(ex, j, 32);
                int sj = __shfl(s, j, 32);
                acc = fmaf(__half2float(h[sj * 32 + f]), w, acc);
            }
        }
    }
#pragma unroll
    for (int off = 16; off; off >>= 1) l += __shfl_xor(l, off, 32);
    out_acc = acc;
    out_l = l;
}

// Mid-layer agg: g = relu(agg + bias), planar fp32 out.
__global__ void agg_mid_kernel(const int* __restrict__ row_ptr,
                               const int* __restrict__ col,
                               const __half* __restrict__ h,
                               const float* __restrict__ es,
                               const float* __restrict__ ed,
                               const float* __restrict__ bias,
                               float* __restrict__ g, int n) {
    int group = (blockIdx.x * blockDim.x + threadIdx.x) >> 5;
    int f = threadIdx.x & 31;
    if (group >= n) return;
    float acc, l;
    agg_core1(row_ptr, col, h, es, ed[group], group, f, acc, l);
    g[group * 32 + f] = fmaxf(acc / l + bias[f], 0.f);
}

// Final agg + relu + linear (+ optional sigmoid), planar out.
__global__ void agg_fin_kernel(const int* __restrict__ row_ptr,
                               const int* __restrict__ col,
                               const __half* __restrict__ h,
                               const float* __restrict__ es,
                               const float* __restrict__ ed,
                               const float* __restrict__ bias,
                               const float* __restrict__ lW,
                               const float* __restrict__ lb,
                               float* __restrict__ out, int n,
                               int do_sigmoid) {
    __shared__ float Ws[32 * 32];
    for (int i = threadIdx.x; i < 32 * 32; i += blockDim.x) Ws[i] = lW[i];
    __syncthreads();
    int group = (blockIdx.x * blockDim.x + threadIdx.x) >> 5;
    int f = threadIdx.x & 31;
    if (group >= n) return;
    float acc, l;
    agg_core1(row_ptr, col, h, es, ed[group], group, f, acc, l);
    float g = fmaxf(acc / l + bias[f], 0.f);
    float y = lb[f];
#pragma unroll
    for (int k = 0; k < 32; ++k) {
        float gk = __shfl(g, k, 32);
        y = fmaf(gk, Ws[k * 32 + f], y);
    }
    if (do_sigmoid) y = 1.f / (1.f + __expf(-y));
    out[group * 32 + f] = y;
}

// ---------------------------------------------------------------------------
// Launch
// ---------------------------------------------------------------------------
extern "C" void kernel_launch(void* const* d_in, const int* in_sizes, int n_in,
                              void* d_out, int out_size, void* d_ws, size_t ws_size,
                              hipStream_t stream) {
    const float* x = (const float*)d_in[0];
    const int* ei = (const int*)d_in[1];   // int32; [src(E), dst(E)]
    const int N = in_sizes[0] / 64;
    const int E = in_sizes[1] / 2;
    const int Etot = E + N;

    const float* cW1  = (const float*)d_in[2];
    const float* cas1 = (const float*)d_in[3];
    const float* cad1 = (const float*)d_in[4];
    const float* cb1  = (const float*)d_in[5];
    const float* cW2  = (const float*)d_in[6];
    const float* cas2 = (const float*)d_in[7];
    const float* cad2 = (const float*)d_in[8];
    const float* cb2  = (const float*)d_in[9];
    const float* clW  = (const float*)d_in[10];
    const float* clb  = (const float*)d_in[11];
    const float* rW1  = (const float*)d_in[12];
    const float* ras1 = (const float*)d_in[13];
    const float* rad1 = (const float*)d_in[14];
    const float* rb1  = (const float*)d_in[15];
    const float* rW2  = (const float*)d_in[16];
    const float* ras2 = (const float*)d_in[17];
    const float* rad2 = (const float*)d_in[18];
    const float* rb2  = (const float*)d_in[19];
    const float* rlW  = (const float*)d_in[20];
    const float* rlb  = (const float*)d_in[21];

    // workspace carve-up (256B aligned); ~27 MB
    char* w = (char*)d_ws;
    size_t off = 0;
    auto alloc = [&](size_t bytes) {
        void* p = w + off;
        off = (off + bytes + 255) & ~(size_t)255;
        return p;
    };
    int*    row_ptr = (int*)alloc((size_t)(N + 1) * 4);
    int*    counts  = (int*)alloc((size_t)N * 4);
    int*    cursor  = (int*)alloc((size_t)N * 4);
    int*    bsum    = (int*)alloc(257 * 4);
    int*    col     = (int*)alloc((size_t)Etot * 4);
    __half* hc      = (__half*)alloc((size_t)N * 32 * 2);  // 3.2 MB, L2-fit
    __half* hr      = (__half*)alloc((size_t)N * 32 * 2);
    float*  gc      = (float*)alloc((size_t)N * 32 * 4);
    float*  gr      = (float*)alloc((size_t)N * 32 * 4);
    float*  esc     = (float*)alloc((size_t)N * 4);
    float*  edc     = (float*)alloc((size_t)N * 4);
    float*  esr     = (float*)alloc((size_t)N * 4);
    float*  edr     = (float*)alloc((size_t)N * 4);
    (void)ws_size;

    float* out = (float*)d_out;

    const int node_blocks = (N * 32 + 255) / 256;
    const int scan_blocks = (N + 255) / 256;   // 196 (<=256 for scan2)

    // ---- CSR build (shared by all 4 GAT layers) ----
    hipMemsetAsync(counts, 0, (size_t)N * 4, stream);
    hist_kernel<<<2048, 256, 0, stream>>>(ei, E, N, counts);
    scan1_kernel<<<scan_blocks, 256, 0, stream>>>(counts, bsum, N);
    scan2_kernel<<<1, 256, 0, stream>>>(bsum, scan_blocks);
    scan3_kernel<<<scan_blocks, 256, 0, stream>>>(counts, bsum, row_ptr, cursor, N, scan_blocks);
    scatter_part_kernel<<<CSR_BLOCKS, 256, 0, stream>>>(ei, E, N, cursor, col);

    // ---- layer 1 ----
    t1_fused_kernel<<<node_blocks, 256, 0, stream>>>(
        x, cW1, rW1, cas1, cad1, ras1, rad1, hc, hr, esc, edc, esr, edr, N);
    agg_mid_kernel<<<node_blocks, 256, 0, stream>>>(
        row_ptr, col, hc, esc, edc, cb1, gc, N);
    agg_mid_kernel<<<node_blocks, 256, 0, stream>>>(
        row_ptr, col, hr, esr, edr, rb1, gr, N);

    // ---- layer 2 + linear head ----
    t2_fused_kernel<<<node_blocks, 256, 0, stream>>>(
        gc, gr, cW2, rW2, cas2, cad2, ras2, rad2, hc, hr, esc, edc, esr, edr, N);
    agg_fin_kernel<<<node_blocks, 256, 0, stream>>>(
        row_ptr, col, hc, esc, edc, cb2, clW, clb, out, N, 1);
    agg_fin_kernel<<<node_blocks, 256, 0, stream>>>(
        row_ptr, col, hr, esr, edr, rb2, rlW, rlb, out + (size_t)N * 32, N, 0);
}